// Round 2
// baseline (565.448 us; speedup 1.0000x reference)
//
#include <hip/hip_runtime.h>

// ---------------------------------------------------------------------------
// SpatialSatCrossAttention (MS deformable attention, 6 cams, 10000 queries)
// ALL float tensors are float32 on the wire (per reference dtypes); vox int32.
// Stages:
//   1. gemm_f32<bf16out> : vproj  = value @ value_W + value_b   (bf16 out, ws)
//   2. gemm_f32          : offlin = query @ off_W + off_b       (f32 out, ws)
//   3. gemm_f32          : attlin = query @ attw_W + attw_b     (f32 out, ws)
//   4. sample_k          : deformable bilinear sampling + softmax + cam mask
//   5. gemm_f32<resid>   : out = slots @ out_W + out_b + query  (f32 d_out)
// ---------------------------------------------------------------------------

typedef unsigned short ushort_t;
typedef unsigned int uint_t;

__device__ __forceinline__ float bf2f(ushort_t u) {
    return __uint_as_float(((uint_t)u) << 16);
}
__device__ __forceinline__ ushort_t f2bf(float f) {
    uint_t i = __float_as_uint(f);
    uint_t r = i + 0x7fffu + ((i >> 16) & 1u);   // round-to-nearest-even
    return (ushort_t)(r >> 16);
}

// ---------------------------------------------------------------------------
// GEMM: C[M,N] = A[M,256] @ W[256,N] + bias[N] (+ resid).  All f32 inputs.
// 64x64 tile, 256 threads, 4x4 microtile, BK=16, f32 accumulate.
// ---------------------------------------------------------------------------
template <bool OUT_BF16, bool RESID>
__global__ __launch_bounds__(256) void gemm_f32(
    const float* __restrict__ A, const float* __restrict__ W,
    const float* __restrict__ bias, const float* __restrict__ resid,
    void* __restrict__ Cv, int M, int N) {
    __shared__ __align__(16) float sA[16][68];
    __shared__ __align__(16) float sB[16][68];

    const int m0 = blockIdx.x * 64;
    const int n0 = blockIdx.y * 64;
    const int t  = threadIdx.x;
    const int tx = t & 15;        // col group
    const int ty = t >> 4;        // row group

    float acc[4][4] = {};

    for (int k0 = 0; k0 < 256; k0 += 16) {
        // --- stage A tile (64 m x 16 k), transposed into sA[k][m] ---
        {
            const int m  = t >> 2;
            const int kq = (t & 3) * 4;
            float4 av = make_float4(0.f, 0.f, 0.f, 0.f);
            const int gm = m0 + m;
            if (gm < M) av = *(const float4*)(A + (size_t)gm * 256 + k0 + kq);
            sA[kq + 0][m] = av.x;
            sA[kq + 1][m] = av.y;
            sA[kq + 2][m] = av.z;
            sA[kq + 3][m] = av.w;
        }
        // --- stage W tile (16 k x 64 n) into sB[k][n] ---
        {
            const int kk = t >> 4;
            const int j  = (t & 15) * 4;
            const float4 bv = *(const float4*)(W + (size_t)(k0 + kk) * N + n0 + j);
            sB[kk][j + 0] = bv.x;
            sB[kk][j + 1] = bv.y;
            sB[kk][j + 2] = bv.z;
            sB[kk][j + 3] = bv.w;
        }
        __syncthreads();

        #pragma unroll
        for (int kk = 0; kk < 16; ++kk) {
            const float4 a4 = *(const float4*)(&sA[kk][ty * 4]);
            const float4 b4 = *(const float4*)(&sB[kk][tx * 4]);
            const float aa[4] = {a4.x, a4.y, a4.z, a4.w};
            const float bb[4] = {b4.x, b4.y, b4.z, b4.w};
            #pragma unroll
            for (int i = 0; i < 4; ++i)
                #pragma unroll
                for (int j = 0; j < 4; ++j)
                    acc[i][j] += aa[i] * bb[j];
        }
        __syncthreads();
    }

    #pragma unroll
    for (int i = 0; i < 4; ++i) {
        const int gm = m0 + ty * 4 + i;
        if (gm >= M) continue;
        #pragma unroll
        for (int j = 0; j < 4; ++j) {
            const int gn = n0 + tx * 4 + j;
            float v = acc[i][j] + bias[gn];
            if (RESID) v += resid[(size_t)gm * N + gn];
            if (OUT_BF16)
                ((ushort_t*)Cv)[(size_t)gm * N + gn] = f2bf(v);
            else
                ((float*)Cv)[(size_t)gm * N + gn] = v;
        }
    }
}

// ---------------------------------------------------------------------------
// Deformable sampling. 1 block per query, 256 threads = 8 heads x 32 chans.
// Thread tid doubles as sample-role (h = tid>>5, lp = tid&31 -> lvl = lp>>3,
// p = lp&7) for index/weight precompute, and as gather-role (h, d = tid&31).
// ---------------------------------------------------------------------------
__global__ __launch_bounds__(256) void sample_k(
    const float* __restrict__ offlin,   // [10000, 512] = [q][h*64+lvl*16+p*2+xy]
    const float* __restrict__ attlin,   // [10000, 256] = [q][h*32+lvl*8+p]
    const float* __restrict__ refp,     // f32 [6,1,10000,4,2]
    const int* __restrict__ vox,        // int32 [6,1,10000,4]
    const ushort_t* __restrict__ vproj, // bf16 [6*5440, 256]
    float* __restrict__ slots) {        // f32 [10000, 256]
    const int q   = blockIdx.x;
    const int tid = threadIdx.x;
    const int h   = tid >> 5;
    const int d   = tid & 31;

    __shared__ float s_valid[8];
    __shared__ int4   s_idx[256];
    __shared__ float4 s_w[256];

    if (tid < 6) {
        const int base = (tid * 10000 + q) * 4;
        const int mm = vox[base] | vox[base + 1] | vox[base + 2] | vox[base + 3];
        s_valid[tid] = mm ? 1.0f : 0.0f;
    }

    // ---- softmax over 32 (lvl,p) entries within each head (32-lane group) ----
    const float a = attlin[(size_t)q * 256 + tid];
    float mx = a;
    #pragma unroll
    for (int o = 16; o >= 1; o >>= 1) mx = fmaxf(mx, __shfl_xor(mx, o));
    const float e = __expf(a - mx);
    float se = e;
    #pragma unroll
    for (int o = 16; o >= 1; o >>= 1) se += __shfl_xor(se, o);
    const float aw = e / se;   // this thread's attention weight for (h,lvl,p)

    // ---- camera-independent part of this thread's sample location ----
    const int lvl = d >> 3;
    const int p   = d & 7;
    const int dd  = p & 3;                     // ref-point index (P//D=2, D=4)
    const int   Sarr[4]   = {64, 32, 16, 8};
    const int   Lstart[4] = {0, 4096, 5120, 5376};
    const int   S  = Sarr[lvl];
    const float Sf = (float)S;
    const int   lstart = Lstart[lvl];
    const float ox = offlin[(size_t)q * 512 + h * 64 + lvl * 16 + p * 2 + 0] / Sf;
    const float oy = offlin[(size_t)q * 512 + h * 64 + lvl * 16 + p * 2 + 1] / Sf;

    __syncthreads();
    const float cnt = s_valid[0] + s_valid[1] + s_valid[2] +
                      s_valid[3] + s_valid[4] + s_valid[5];

    float acc = 0.0f;
    for (int c = 0; c < 6; ++c) {
        if (s_valid[c] == 0.0f) continue;   // block-uniform branch

        // ---- this thread's (h,lvl,p) sample: 4 corner indices + weights ----
        const int rbase = ((c * 10000 + q) * 4 + dd) * 2;
        const float rx = refp[rbase + 0];
        const float ry = refp[rbase + 1];
        const float x  = (rx + ox) * Sf - 0.5f;
        const float y  = (ry + oy) * Sf - 0.5f;
        const float x0 = floorf(x), y0 = floorf(y);

        int   ci[4];
        float cw[4];
        #pragma unroll
        for (int k = 0; k < 4; ++k) {
            const float cx = x0 + (float)(k & 1);
            const float cy = y0 + (float)(k >> 1);
            const float wgt = (1.0f - fabsf(x - cx)) * (1.0f - fabsf(y - cy));
            const bool ok = (cx >= 0.0f) & (cx < Sf) & (cy >= 0.0f) & (cy < Sf);
            const int xi = (int)fminf(fmaxf(cx, 0.0f), Sf - 1.0f);
            const int yi = (int)fminf(fmaxf(cy, 0.0f), Sf - 1.0f);
            ci[k] = (c * 5440 + lstart + yi * S + xi) * 256 + h * 32;  // + d later
            cw[k] = ok ? wgt * aw : 0.0f;
        }
        s_idx[tid] = make_int4(ci[0], ci[1], ci[2], ci[3]);
        s_w[tid]   = make_float4(cw[0], cw[1], cw[2], cw[3]);
        __syncthreads();

        // ---- gather: channel tid = h*32+d over all 32 (lvl,p) of this head ----
        #pragma unroll 4
        for (int lp = 0; lp < 32; ++lp) {
            const int el = h * 32 + lp;
            const int4   ii = s_idx[el];   // broadcast within head group
            const float4 ww = s_w[el];
            acc += ww.x * bf2f(vproj[ii.x + d]);
            acc += ww.y * bf2f(vproj[ii.y + d]);
            acc += ww.z * bf2f(vproj[ii.z + d]);
            acc += ww.w * bf2f(vproj[ii.w + d]);
        }
        __syncthreads();
    }

    slots[(size_t)q * 256 + tid] = acc / fmaxf(cnt, 1.0f);
}

// ---------------------------------------------------------------------------
extern "C" void kernel_launch(void* const* d_in, const int* in_sizes, int n_in,
                              void* d_out, int out_size, void* d_ws, size_t ws_size,
                              hipStream_t stream) {
    const float* query   = (const float*)d_in[0];
    // d_in[1] = key : unused by the deformable-attention math
    const float* value   = (const float*)d_in[2];   // (6,5440,1,256) -> (32640,256)
    const float* refp    = (const float*)d_in[3];
    const int*   vox     = (const int*)d_in[4];
    // d_in[5] spatial_shapes, d_in[6] level_start_index : compile-time constants
    const float* value_W = (const float*)d_in[7];
    const float* value_b = (const float*)d_in[8];
    const float* off_W   = (const float*)d_in[9];
    const float* off_b   = (const float*)d_in[10];
    const float* attw_W  = (const float*)d_in[11];
    const float* attw_b  = (const float*)d_in[12];
    const float* out_W   = (const float*)d_in[13];
    const float* out_b   = (const float*)d_in[14];
    float* out = (float*)d_out;

    // workspace layout (bytes): vproj bf16 16,711,680 | offlin f32 20,480,000
    //                           attlin f32 10,240,000 | slots f32 10,240,000
    char* ws = (char*)d_ws;
    ushort_t* vproj = (ushort_t*)ws;
    float* offlin = (float*)(ws + 16711680);
    float* attlin = (float*)(ws + 16711680 + 20480000);
    float* slots  = (float*)(ws + 16711680 + 20480000 + 10240000);

    // 1. value projection: 32640 x 256 x 256, bf16 out
    gemm_f32<true, false><<<dim3(510, 4), 256, 0, stream>>>(
        value, value_W, value_b, nullptr, (void*)vproj, 32640, 256);
    // 2. offset projection: 10000 x 256 x 512, f32 out
    gemm_f32<false, false><<<dim3(157, 8), 256, 0, stream>>>(
        query, off_W, off_b, nullptr, (void*)offlin, 10000, 512);
    // 3. attention-weight projection: 10000 x 256 x 256, f32 out
    gemm_f32<false, false><<<dim3(157, 4), 256, 0, stream>>>(
        query, attw_W, attw_b, nullptr, (void*)attlin, 10000, 256);
    // 4. deformable sampling + softmax + camera mask/count
    sample_k<<<10000, 256, 0, stream>>>(offlin, attlin, refp, vox, vproj, slots);
    // 5. output projection + residual, f32 out
    gemm_f32<false, true><<<dim3(157, 4), 256, 0, stream>>>(
        slots, out_W, out_b, query, (void*)out, 10000, 256);
}

// Round 3
// 450.222 us; speedup vs baseline: 1.2559x; 1.2559x over previous
//
#include <hip/hip_runtime.h>

// ---------------------------------------------------------------------------
// SpatialSatCrossAttention (MS deformable attention, 6 cams, 10000 queries)
// ALL float tensors are float32 on the wire (per reference dtypes); vox int32.
// Stages:
//   1. gemm_f32<bf16out> : vproj  = value @ value_W + value_b   (bf16 out, ws)
//   2. gemm_f32          : offlin = query @ off_W + off_b       (f32 out, ws)
//   3. gemm_f32          : attlin = query @ attw_W + attw_b     (f32 out, ws)
//   4. sample_k          : deformable bilinear sampling + softmax + cam mask
//   5. gemm_f32<resid>   : out = slots @ out_W + out_b + query  (f32 d_out)
// ---------------------------------------------------------------------------

typedef unsigned short ushort_t;
typedef unsigned int uint_t;

__device__ __forceinline__ float bf2f(ushort_t u) {
    return __uint_as_float(((uint_t)u) << 16);
}
__device__ __forceinline__ ushort_t f2bf(float f) {
    uint_t i = __float_as_uint(f);
    uint_t r = i + 0x7fffu + ((i >> 16) & 1u);   // round-to-nearest-even
    return (ushort_t)(r >> 16);
}

// ---------------------------------------------------------------------------
// GEMM: C[M,N] = A[M,256] @ W[256,N] + bias[N] (+ resid).  All f32 inputs.
// 64x64 tile, 256 threads, 4x4 microtile, BK=16, f32 accumulate.
// ---------------------------------------------------------------------------
template <bool OUT_BF16, bool RESID>
__global__ __launch_bounds__(256) void gemm_f32(
    const float* __restrict__ A, const float* __restrict__ W,
    const float* __restrict__ bias, const float* __restrict__ resid,
    void* __restrict__ Cv, int M, int N) {
    __shared__ __align__(16) float sA[16][68];
    __shared__ __align__(16) float sB[16][68];

    const int m0 = blockIdx.x * 64;
    const int n0 = blockIdx.y * 64;
    const int t  = threadIdx.x;
    const int tx = t & 15;        // col group
    const int ty = t >> 4;        // row group

    float acc[4][4] = {};

    for (int k0 = 0; k0 < 256; k0 += 16) {
        // --- stage A tile (64 m x 16 k), transposed into sA[k][m] ---
        {
            const int m  = t >> 2;
            const int kq = (t & 3) * 4;
            float4 av = make_float4(0.f, 0.f, 0.f, 0.f);
            const int gm = m0 + m;
            if (gm < M) av = *(const float4*)(A + (size_t)gm * 256 + k0 + kq);
            sA[kq + 0][m] = av.x;
            sA[kq + 1][m] = av.y;
            sA[kq + 2][m] = av.z;
            sA[kq + 3][m] = av.w;
        }
        // --- stage W tile (16 k x 64 n) into sB[k][n] ---
        {
            const int kk = t >> 4;
            const int j  = (t & 15) * 4;
            const float4 bv = *(const float4*)(W + (size_t)(k0 + kk) * N + n0 + j);
            sB[kk][j + 0] = bv.x;
            sB[kk][j + 1] = bv.y;
            sB[kk][j + 2] = bv.z;
            sB[kk][j + 3] = bv.w;
        }
        __syncthreads();

        #pragma unroll
        for (int kk = 0; kk < 16; ++kk) {
            const float4 a4 = *(const float4*)(&sA[kk][ty * 4]);
            const float4 b4 = *(const float4*)(&sB[kk][tx * 4]);
            const float aa[4] = {a4.x, a4.y, a4.z, a4.w};
            const float bb[4] = {b4.x, b4.y, b4.z, b4.w};
            #pragma unroll
            for (int i = 0; i < 4; ++i)
                #pragma unroll
                for (int j = 0; j < 4; ++j)
                    acc[i][j] += aa[i] * bb[j];
        }
        __syncthreads();
    }

    #pragma unroll
    for (int i = 0; i < 4; ++i) {
        const int gm = m0 + ty * 4 + i;
        if (gm >= M) continue;
        #pragma unroll
        for (int j = 0; j < 4; ++j) {
            const int gn = n0 + tx * 4 + j;
            float v = acc[i][j] + bias[gn];
            if (RESID) v += resid[(size_t)gm * N + gn];
            if (OUT_BF16)
                ((ushort_t*)Cv)[(size_t)gm * N + gn] = f2bf(v);
            else
                ((float*)Cv)[(size_t)gm * N + gn] = v;
        }
    }
}

// ---------------------------------------------------------------------------
// Deformable sampling. 1 block per query, 256 threads.
// Thread tid = h*32 + slice*4 + g  (h: head, slice: 8 lp-slices, g: 8-chan grp)
//   setup role : (h, lp = tid&31)  -> corner idx/weights for its (h,lvl,p)
//   gather role: (h, slice, g)     -> 16B dwordx4 loads of 8 bf16 channels,
//                                     over lp = slice*4 .. slice*4+3
// Per-corner idx/weight tables in LDS (writes conflict-free, reads broadcast).
// Cross-slice reduction through an 8 KB LDS tile at the end.
// ---------------------------------------------------------------------------
__global__ __launch_bounds__(256) void sample_k(
    const float* __restrict__ offlin,   // [10000, 512] = [q][h*64+lvl*16+p*2+xy]
    const float* __restrict__ attlin,   // [10000, 256] = [q][h*32+lvl*8+p]
    const float* __restrict__ refp,     // f32 [6,1,10000,4,2]
    const int* __restrict__ vox,        // int32 [6,1,10000,4]
    const ushort_t* __restrict__ vproj, // bf16 [6*5440, 256]
    float* __restrict__ slots) {        // f32 [10000, 256]
    const int q   = blockIdx.x;
    const int tid = threadIdx.x;
    const int h     = tid >> 5;
    const int lp    = tid & 31;          // setup role
    const int slice = (tid >> 2) & 7;    // gather role
    const int g     = tid & 3;           // gather role: channels g*8..g*8+7

    __shared__ float s_valid[8];
    __shared__ int   s_ci[4][256];       // [corner][h*32+lp]
    __shared__ float s_cw[4][256];
    __shared__ float s_red[256][8];      // [tid][chan-in-group]

    if (tid < 6) {
        const int base = (tid * 10000 + q) * 4;
        const int mm = vox[base] | vox[base + 1] | vox[base + 2] | vox[base + 3];
        s_valid[tid] = mm ? 1.0f : 0.0f;
    }

    // ---- softmax over 32 (lvl,p) entries within each head (32-lane group) ----
    const float a = attlin[(size_t)q * 256 + tid];
    float mx = a;
    #pragma unroll
    for (int o = 16; o >= 1; o >>= 1) mx = fmaxf(mx, __shfl_xor(mx, o));
    const float e = __expf(a - mx);
    float se = e;
    #pragma unroll
    for (int o = 16; o >= 1; o >>= 1) se += __shfl_xor(se, o);
    const float aw = e / se;   // attention weight for this thread's (h,lvl,p)

    // ---- camera-independent part of this thread's sample location ----
    const int lvl = lp >> 3;
    const int p   = lp & 7;
    const int dd  = p & 3;                     // ref-point index (P//D=2, D=4)
    const int   Sarr[4]   = {64, 32, 16, 8};
    const int   Lstart[4] = {0, 4096, 5120, 5376};
    const int   S  = Sarr[lvl];
    const float Sf = (float)S;
    const int   lstart = Lstart[lvl];
    const float ox = offlin[(size_t)q * 512 + h * 64 + lvl * 16 + p * 2 + 0] / Sf;
    const float oy = offlin[(size_t)q * 512 + h * 64 + lvl * 16 + p * 2 + 1] / Sf;

    __syncthreads();
    const float cnt = s_valid[0] + s_valid[1] + s_valid[2] +
                      s_valid[3] + s_valid[4] + s_valid[5];

    float acc[8] = {};
    const int gofs = g << 3;   // channel offset within head

    for (int c = 0; c < 6; ++c) {
        if (s_valid[c] == 0.0f) continue;   // block-uniform branch

        // ---- setup: this (h,lvl,p) sample's 4 corner indices + weights ----
        {
            const int rbase = ((c * 10000 + q) * 4 + dd) * 2;
            const float rx = refp[rbase + 0];
            const float ry = refp[rbase + 1];
            const float x  = (rx + ox) * Sf - 0.5f;
            const float y  = (ry + oy) * Sf - 0.5f;
            const float x0 = floorf(x), y0 = floorf(y);
            #pragma unroll
            for (int k = 0; k < 4; ++k) {
                const float cx = x0 + (float)(k & 1);
                const float cy = y0 + (float)(k >> 1);
                const float wgt = (1.0f - fabsf(x - cx)) * (1.0f - fabsf(y - cy));
                const bool ok = (cx >= 0.0f) & (cx < Sf) & (cy >= 0.0f) & (cy < Sf);
                const int xi = (int)fminf(fmaxf(cx, 0.0f), Sf - 1.0f);
                const int yi = (int)fminf(fmaxf(cy, 0.0f), Sf - 1.0f);
                s_ci[k][tid] = (c * 5440 + lstart + yi * S + xi) * 256 + h * 32;
                s_cw[k][tid] = ok ? wgt * aw : 0.0f;
            }
        }
        __syncthreads();

        // ---- gather: 4 lp x 4 corners, 16B (8 bf16 chans) per load ----
        #pragma unroll
        for (int j = 0; j < 4; ++j) {
            const int el = h * 32 + slice * 4 + j;
            #pragma unroll
            for (int k = 0; k < 4; ++k) {
                const int   idx = s_ci[k][el];
                const float w   = s_cw[k][el];
                const uint4 v = *(const uint4*)(vproj + idx + gofs);
                acc[0] += w * __uint_as_float(v.x << 16);
                acc[1] += w * __uint_as_float(v.x & 0xffff0000u);
                acc[2] += w * __uint_as_float(v.y << 16);
                acc[3] += w * __uint_as_float(v.y & 0xffff0000u);
                acc[4] += w * __uint_as_float(v.z << 16);
                acc[5] += w * __uint_as_float(v.z & 0xffff0000u);
                acc[6] += w * __uint_as_float(v.w << 16);
                acc[7] += w * __uint_as_float(v.w & 0xffff0000u);
            }
        }
        __syncthreads();
    }

    // ---- cross-slice reduction: acc[(h,slice,g)][e] -> out[(h, g*8+e)] ----
    #pragma unroll
    for (int e2 = 0; e2 < 8; ++e2) s_red[tid][e2] = acc[e2];
    __syncthreads();

    // reader: tid = h*32 + cch; sums 8 slices of channel cch
    const int cch = tid & 31;
    float sum = 0.0f;
    #pragma unroll
    for (int s = 0; s < 8; ++s)
        sum += s_red[h * 32 + s * 4 + (cch >> 3)][cch & 7];

    slots[(size_t)q * 256 + tid] = sum / fmaxf(cnt, 1.0f);
}

// ---------------------------------------------------------------------------
extern "C" void kernel_launch(void* const* d_in, const int* in_sizes, int n_in,
                              void* d_out, int out_size, void* d_ws, size_t ws_size,
                              hipStream_t stream) {
    const float* query   = (const float*)d_in[0];
    // d_in[1] = key : unused by the deformable-attention math
    const float* value   = (const float*)d_in[2];   // (6,5440,1,256) -> (32640,256)
    const float* refp    = (const float*)d_in[3];
    const int*   vox     = (const int*)d_in[4];
    // d_in[5] spatial_shapes, d_in[6] level_start_index : compile-time constants
    const float* value_W = (const float*)d_in[7];
    const float* value_b = (const float*)d_in[8];
    const float* off_W   = (const float*)d_in[9];
    const float* off_b   = (const float*)d_in[10];
    const float* attw_W  = (const float*)d_in[11];
    const float* attw_b  = (const float*)d_in[12];
    const float* out_W   = (const float*)d_in[13];
    const float* out_b   = (const float*)d_in[14];
    float* out = (float*)d_out;

    // workspace layout (bytes): vproj bf16 16,711,680 | offlin f32 20,480,000
    //                           attlin f32 10,240,000 | slots f32 10,240,000
    char* ws = (char*)d_ws;
    ushort_t* vproj = (ushort_t*)ws;
    float* offlin = (float*)(ws + 16711680);
    float* attlin = (float*)(ws + 16711680 + 20480000);
    float* slots  = (float*)(ws + 16711680 + 20480000 + 10240000);

    // 1. value projection: 32640 x 256 x 256, bf16 out
    gemm_f32<true, false><<<dim3(510, 4), 256, 0, stream>>>(
        value, value_W, value_b, nullptr, (void*)vproj, 32640, 256);
    // 2. offset projection: 10000 x 256 x 512, f32 out
    gemm_f32<false, false><<<dim3(157, 8), 256, 0, stream>>>(
        query, off_W, off_b, nullptr, (void*)offlin, 10000, 512);
    // 3. attention-weight projection: 10000 x 256 x 256, f32 out
    gemm_f32<false, false><<<dim3(157, 4), 256, 0, stream>>>(
        query, attw_W, attw_b, nullptr, (void*)attlin, 10000, 256);
    // 4. deformable sampling + softmax + camera mask/count
    sample_k<<<10000, 256, 0, stream>>>(offlin, attlin, refp, vox, vproj, slots);
    // 5. output projection + residual, f32 out
    gemm_f32<false, true><<<dim3(157, 4), 256, 0, stream>>>(
        slots, out_W, out_b, query, (void*)out, 10000, 256);
}

// Round 4
// 388.188 us; speedup vs baseline: 1.4566x; 1.1598x over previous
//
#include <hip/hip_runtime.h>

// ---------------------------------------------------------------------------
// SpatialSatCrossAttention (MS deformable attention, 6 cams, 10000 queries)
// ALL float tensors are float32 on the wire; vox int32.
// Stages:
//   0. transpose_w       : all 4 weight mats -> Wt[n][k] bf16 in ws (1 launch)
//   1. gemm_mfma<bf16>   : vproj  = value @ value_W + value_b   (bf16 out, ws)
//   2. gemm_mfma         : offlin = query @ off_W + off_b       (f32 out, ws)
//   3. gemm_mfma         : attlin = query @ attw_W + attw_b     (f32 out, ws)
//   4. sample_k          : deformable bilinear sampling + softmax + cam mask
//   5. gemm_mfma<resid>  : out = slots @ out_W + out_b + query  (f32 d_out)
// GEMMs: 128x128 tile, 4 waves (2x2), 4x4 mfma_f32_16x16x32_bf16 per wave,
// BK=32, f32 accumulate. A is f32->bf16 converted during LDS staging.
// ---------------------------------------------------------------------------

typedef unsigned short ushort_t;
typedef unsigned int uint_t;
typedef __attribute__((ext_vector_type(8))) short bf16x8;
typedef __attribute__((ext_vector_type(4))) float f32x4;

__device__ __forceinline__ float bf2f(ushort_t u) {
    return __uint_as_float(((uint_t)u) << 16);
}
__device__ __forceinline__ ushort_t f2bf(float f) {
    uint_t i = __float_as_uint(f);
    uint_t r = i + 0x7fffu + ((i >> 16) & 1u);   // round-to-nearest-even
    return (ushort_t)(r >> 16);
}

// ---------------------------------------------------------------------------
// Weight transpose+convert: W[k][N] f32 -> Wt[n][256] bf16.  One launch for
// all four weight matrices (blockIdx.z selects), 32x32 LDS tiles.
// grid (256/32, 512/32, 4), block 256.
// ---------------------------------------------------------------------------
__global__ __launch_bounds__(256) void transpose_w(
    const float* __restrict__ W0, const float* __restrict__ W1,
    const float* __restrict__ W2, const float* __restrict__ W3,
    ushort_t* __restrict__ T0, ushort_t* __restrict__ T1,
    ushort_t* __restrict__ T2, ushort_t* __restrict__ T3) {
    const int z = blockIdx.z;
    const float* W;
    ushort_t* T;
    int N;
    if (z == 0)      { W = W0; T = T0; N = 256; }
    else if (z == 1) { W = W1; T = T1; N = 256; }
    else if (z == 2) { W = W2; T = T2; N = 256; }
    else             { W = W3; T = T3; N = 512; }
    const int n0 = blockIdx.y * 32;
    if (n0 >= N) return;
    const int k0 = blockIdx.x * 32;

    __shared__ float tile[32][33];
    const int tx = threadIdx.x & 31;
    const int ty = threadIdx.x >> 5;   // 0..7

    #pragma unroll
    for (int r = 0; r < 4; ++r) {
        const int k = ty + r * 8;
        tile[k][tx] = W[(size_t)(k0 + k) * N + n0 + tx];
    }
    __syncthreads();
    #pragma unroll
    for (int r = 0; r < 4; ++r) {
        const int n = ty + r * 8;
        T[(size_t)(n0 + n) * 256 + k0 + tx] = f2bf(tile[tx][n]);
    }
}

// ---------------------------------------------------------------------------
// MFMA GEMM: C[M,N] = A[M,256] @ W[256,N] + bias (+resid).
// A f32 row-major; Wt bf16 [N][256] (pre-transposed). N multiple of 128.
// ---------------------------------------------------------------------------
template <bool OUT_BF16, bool RESID>
__global__ __launch_bounds__(256) void gemm_mfma(
    const float* __restrict__ A, const ushort_t* __restrict__ Wt,
    const float* __restrict__ bias, const float* __restrict__ resid,
    void* __restrict__ Cv, int M, int N) {
    __shared__ ushort_t sA[128][40];   // row stride 80 B (2-way bank alias: free)
    __shared__ ushort_t sB[128][40];

    const int m0 = blockIdx.x * 128;
    const int n0 = blockIdx.y * 128;
    const int t    = threadIdx.x;
    const int lane = t & 63;
    const int w    = t >> 6;
    const int wr   = w >> 1, wc = w & 1;

    f32x4 acc[4][4];
    #pragma unroll
    for (int i = 0; i < 4; ++i)
        #pragma unroll
        for (int j = 0; j < 4; ++j)
            acc[i][j] = (f32x4){0.f, 0.f, 0.f, 0.f};

    const int srow = t >> 2;          // 0..63
    const int skof = (t & 3) * 8;     // 0,8,16,24

    for (int k0 = 0; k0 < 256; k0 += 32) {
        #pragma unroll
        for (int r = 0; r < 2; ++r) {
            const int row = r * 64 + srow;
            // --- stage A (f32 -> bf16) ---
            {
                const int gm = m0 + row;
                float4 v0 = make_float4(0.f, 0.f, 0.f, 0.f);
                float4 v1 = v0;
                if (gm < M) {
                    const float* src = A + (size_t)gm * 256 + k0 + skof;
                    v0 = *(const float4*)(src);
                    v1 = *(const float4*)(src + 4);
                }
                bf16x8 pk = {
                    (short)f2bf(v0.x), (short)f2bf(v0.y),
                    (short)f2bf(v0.z), (short)f2bf(v0.w),
                    (short)f2bf(v1.x), (short)f2bf(v1.y),
                    (short)f2bf(v1.z), (short)f2bf(v1.w)};
                *(bf16x8*)(&sA[row][skof]) = pk;
            }
            // --- stage B (bf16 16-B copy; N % 128 == 0, no guard) ---
            {
                const int gn = n0 + row;
                const bf16x8 pk =
                    *(const bf16x8*)(Wt + (size_t)gn * 256 + k0 + skof);
                *(bf16x8*)(&sB[row][skof]) = pk;
            }
        }
        __syncthreads();

        bf16x8 af[4], bfr[4];
        const int kq = (lane >> 4) * 8;
        const int rl = lane & 15;
        #pragma unroll
        for (int i = 0; i < 4; ++i)
            af[i] = *(const bf16x8*)(&sA[wr * 64 + i * 16 + rl][kq]);
        #pragma unroll
        for (int j = 0; j < 4; ++j)
            bfr[j] = *(const bf16x8*)(&sB[wc * 64 + j * 16 + rl][kq]);
        #pragma unroll
        for (int i = 0; i < 4; ++i)
            #pragma unroll
            for (int j = 0; j < 4; ++j)
                acc[i][j] = __builtin_amdgcn_mfma_f32_16x16x32_bf16(
                    af[i], bfr[j], acc[i][j], 0, 0, 0);
        __syncthreads();
    }

    // --- epilogue: C/D layout col=lane&15, row=(lane>>4)*4+reg (m89) ---
    const int col_l = lane & 15;
    const int rq    = (lane >> 4) * 4;
    #pragma unroll
    for (int j = 0; j < 4; ++j) {
        const int gn = n0 + wc * 64 + j * 16 + col_l;
        const float bj = bias[gn];
        #pragma unroll
        for (int i = 0; i < 4; ++i) {
            #pragma unroll
            for (int r = 0; r < 4; ++r) {
                const int gm = m0 + wr * 64 + i * 16 + rq + r;
                if (gm >= M) continue;
                float v = acc[i][j][r] + bj;
                if (RESID) v += resid[(size_t)gm * N + gn];
                if (OUT_BF16)
                    ((ushort_t*)Cv)[(size_t)gm * N + gn] = f2bf(v);
                else
                    ((float*)Cv)[(size_t)gm * N + gn] = v;
            }
        }
    }
}

// ---------------------------------------------------------------------------
// Deformable sampling. 1 block per query, 256 threads.
// Thread tid = h*32 + slice*4 + g  (h: head, slice: 8 lp-slices, g: 8-chan grp)
//   setup role : (h, lp = tid&31)  -> corner idx/weights for its (h,lvl,p)
//   gather role: (h, slice, g)     -> 16B dwordx4 loads of 8 bf16 channels,
//                                     over lp = slice*4 .. slice*4+3
// ---------------------------------------------------------------------------
__global__ __launch_bounds__(256) void sample_k(
    const float* __restrict__ offlin,   // [10000, 512]
    const float* __restrict__ attlin,   // [10000, 256]
    const float* __restrict__ refp,     // f32 [6,1,10000,4,2]
    const int* __restrict__ vox,        // int32 [6,1,10000,4]
    const ushort_t* __restrict__ vproj, // bf16 [6*5440, 256]
    float* __restrict__ slots) {        // f32 [10000, 256]
    const int q   = blockIdx.x;
    const int tid = threadIdx.x;
    const int h     = tid >> 5;
    const int lp    = tid & 31;          // setup role
    const int slice = (tid >> 2) & 7;    // gather role
    const int g     = tid & 3;           // gather role: channels g*8..g*8+7

    __shared__ float s_valid[8];
    __shared__ int   s_ci[4][256];       // [corner][h*32+lp]
    __shared__ float s_cw[4][256];
    __shared__ float s_red[256][8];      // [tid][chan-in-group]

    if (tid < 6) {
        const int base = (tid * 10000 + q) * 4;
        const int mm = vox[base] | vox[base + 1] | vox[base + 2] | vox[base + 3];
        s_valid[tid] = mm ? 1.0f : 0.0f;
    }

    // ---- softmax over 32 (lvl,p) entries within each head ----
    const float a = attlin[(size_t)q * 256 + tid];
    float mx = a;
    #pragma unroll
    for (int o = 16; o >= 1; o >>= 1) mx = fmaxf(mx, __shfl_xor(mx, o));
    const float e = __expf(a - mx);
    float se = e;
    #pragma unroll
    for (int o = 16; o >= 1; o >>= 1) se += __shfl_xor(se, o);
    const float aw = e / se;

    // ---- camera-independent part of this thread's sample location ----
    const int lvl = lp >> 3;
    const int p   = lp & 7;
    const int dd  = p & 3;
    const int   Sarr[4]   = {64, 32, 16, 8};
    const int   Lstart[4] = {0, 4096, 5120, 5376};
    const int   S  = Sarr[lvl];
    const float Sf = (float)S;
    const int   lstart = Lstart[lvl];
    const float ox = offlin[(size_t)q * 512 + h * 64 + lvl * 16 + p * 2 + 0] / Sf;
    const float oy = offlin[(size_t)q * 512 + h * 64 + lvl * 16 + p * 2 + 1] / Sf;

    __syncthreads();
    const float cnt = s_valid[0] + s_valid[1] + s_valid[2] +
                      s_valid[3] + s_valid[4] + s_valid[5];

    float acc[8] = {};
    const int gofs = g << 3;

    for (int c = 0; c < 6; ++c) {
        if (s_valid[c] == 0.0f) continue;   // block-uniform branch

        {
            const int rbase = ((c * 10000 + q) * 4 + dd) * 2;
            const float rx = refp[rbase + 0];
            const float ry = refp[rbase + 1];
            const float x  = (rx + ox) * Sf - 0.5f;
            const float y  = (ry + oy) * Sf - 0.5f;
            const float x0 = floorf(x), y0 = floorf(y);
            #pragma unroll
            for (int k = 0; k < 4; ++k) {
                const float cx = x0 + (float)(k & 1);
                const float cy = y0 + (float)(k >> 1);
                const float wgt = (1.0f - fabsf(x - cx)) * (1.0f - fabsf(y - cy));
                const bool ok = (cx >= 0.0f) & (cx < Sf) & (cy >= 0.0f) & (cy < Sf);
                const int xi = (int)fminf(fmaxf(cx, 0.0f), Sf - 1.0f);
                const int yi = (int)fminf(fmaxf(cy, 0.0f), Sf - 1.0f);
                s_ci[k][tid] = (c * 5440 + lstart + yi * S + xi) * 256 + h * 32;
                s_cw[k][tid] = ok ? wgt * aw : 0.0f;
            }
        }
        __syncthreads();

        #pragma unroll
        for (int j = 0; j < 4; ++j) {
            const int el = h * 32 + slice * 4 + j;
            #pragma unroll
            for (int k = 0; k < 4; ++k) {
                const int   idx = s_ci[k][el];
                const float wv  = s_cw[k][el];
                const uint4 v = *(const uint4*)(vproj + idx + gofs);
                acc[0] += wv * __uint_as_float(v.x << 16);
                acc[1] += wv * __uint_as_float(v.x & 0xffff0000u);
                acc[2] += wv * __uint_as_float(v.y << 16);
                acc[3] += wv * __uint_as_float(v.y & 0xffff0000u);
                acc[4] += wv * __uint_as_float(v.z << 16);
                acc[5] += wv * __uint_as_float(v.z & 0xffff0000u);
                acc[6] += wv * __uint_as_float(v.w << 16);
                acc[7] += wv * __uint_as_float(v.w & 0xffff0000u);
            }
        }
        __syncthreads();
    }

    // ---- cross-slice reduction ----
    #pragma unroll
    for (int e2 = 0; e2 < 8; ++e2) s_red[tid][e2] = acc[e2];
    __syncthreads();

    const int cch = tid & 31;
    float sum = 0.0f;
    #pragma unroll
    for (int s = 0; s < 8; ++s)
        sum += s_red[h * 32 + s * 4 + (cch >> 3)][cch & 7];

    slots[(size_t)q * 256 + tid] = sum / fmaxf(cnt, 1.0f);
}

// ---------------------------------------------------------------------------
extern "C" void kernel_launch(void* const* d_in, const int* in_sizes, int n_in,
                              void* d_out, int out_size, void* d_ws, size_t ws_size,
                              hipStream_t stream) {
    const float* query   = (const float*)d_in[0];
    // d_in[1] = key : unused by the deformable-attention math
    const float* value   = (const float*)d_in[2];   // (6,5440,1,256) -> (32640,256)
    const float* refp    = (const float*)d_in[3];
    const int*   vox     = (const int*)d_in[4];
    // d_in[5] spatial_shapes, d_in[6] level_start_index : compile-time constants
    const float* value_W = (const float*)d_in[7];
    const float* value_b = (const float*)d_in[8];
    const float* off_W   = (const float*)d_in[9];
    const float* off_b   = (const float*)d_in[10];
    const float* attw_W  = (const float*)d_in[11];
    const float* attw_b  = (const float*)d_in[12];
    const float* out_W   = (const float*)d_in[13];
    const float* out_b   = (const float*)d_in[14];
    float* out = (float*)d_out;

    // ws layout (bytes):
    //   vproj  bf16 16,711,680
    //   offlin f32  20,480,000
    //   attlin f32  10,240,000
    //   slots  f32  10,240,000
    //   value_Wt bf16 131,072 | off_Wt 262,144 | attw_Wt 131,072 | out_Wt 131,072
    char* ws = (char*)d_ws;
    ushort_t* vproj = (ushort_t*)ws;
    float* offlin = (float*)(ws + 16711680);
    float* attlin = (float*)(ws + 16711680 + 20480000);
    float* slots  = (float*)(ws + 16711680 + 20480000 + 10240000);
    char* wtb = ws + 16711680 + 20480000 + 10240000 + 10240000;
    ushort_t* value_Wt = (ushort_t*)(wtb);
    ushort_t* attw_Wt  = (ushort_t*)(wtb + 131072);
    ushort_t* out_Wt   = (ushort_t*)(wtb + 262144);
    ushort_t* off_Wt   = (ushort_t*)(wtb + 393216);

    // 0. transpose+convert all weights -> Wt[n][k] bf16
    transpose_w<<<dim3(8, 16, 4), 256, 0, stream>>>(
        value_W, attw_W, out_W, off_W, value_Wt, attw_Wt, out_Wt, off_Wt);
    // 1. value projection: 32640 x 256 x 256, bf16 out
    gemm_mfma<true, false><<<dim3(255, 2), 256, 0, stream>>>(
        value, value_Wt, value_b, nullptr, (void*)vproj, 32640, 256);
    // 2. offset projection: 10000 x 256 x 512, f32 out
    gemm_mfma<false, false><<<dim3(79, 4), 256, 0, stream>>>(
        query, off_Wt, off_b, nullptr, (void*)offlin, 10000, 512);
    // 3. attention-weight projection: 10000 x 256 x 256, f32 out
    gemm_mfma<false, false><<<dim3(79, 2), 256, 0, stream>>>(
        query, attw_Wt, attw_b, nullptr, (void*)attlin, 10000, 256);
    // 4. deformable sampling + softmax + camera mask/count
    sample_k<<<10000, 256, 0, stream>>>(offlin, attlin, refp, vox, vproj, slots);
    // 5. output projection + residual, f32 out
    gemm_mfma<false, true><<<dim3(79, 2), 256, 0, stream>>>(
        slots, out_Wt, out_b, query, (void*)out, 10000, 256);
}

// Round 5
// 358.323 us; speedup vs baseline: 1.5780x; 1.0833x over previous
//
#include <hip/hip_runtime.h>

// ---------------------------------------------------------------------------
// SpatialSatCrossAttention (MS deformable attention, 6 cams, 10000 queries)
// ALL float tensors are float32 on the wire; vox int32.
// Stages:
//   1,2. cvt_bf16        : value, query -> bf16 copies in ws
//   3. transpose_w       : 4 weight mats -> Wt[n][k] bf16 (off+attw fused)
//   4. gemm_mfma<bf16>   : vproj  = value_bf @ value_W + b     (bf16, ws)
//   5. gemm_mfma         : qkcat  = query_bf @ [off_W|attw_W]  (f32, ws, N=768)
//   6. sample_k          : deformable bilinear sampling -> slots bf16
//   7. gemm_mfma<resid>  : out = slots_bf @ out_W + out_b + query (f32 d_out)
// GEMM: 128x128 tile, 4 waves (2x2), 4x4 mfma_f32_16x16x32_bf16, BK=32,
// double-buffered LDS + register prefetch (loads for k+1 issue before MFMA k).
// ---------------------------------------------------------------------------

typedef unsigned short ushort_t;
typedef unsigned int uint_t;
typedef __attribute__((ext_vector_type(8))) short bf16x8;
typedef __attribute__((ext_vector_type(4))) float f32x4;

__device__ __forceinline__ float bf2f(ushort_t u) {
    return __uint_as_float(((uint_t)u) << 16);
}
__device__ __forceinline__ ushort_t f2bf(float f) {
    uint_t i = __float_as_uint(f);
    uint_t r = i + 0x7fffu + ((i >> 16) & 1u);   // round-to-nearest-even
    return (ushort_t)(r >> 16);
}

// ---------------------------------------------------------------------------
// Elementwise f32 -> bf16 (8 elems/thread).
// ---------------------------------------------------------------------------
__global__ __launch_bounds__(256) void cvt_bf16(
    const float* __restrict__ src, ushort_t* __restrict__ dst, int n8) {
    const int i = blockIdx.x * 256 + threadIdx.x;
    if (i >= n8) return;
    const float4 v0 = *(const float4*)(src + (size_t)i * 8);
    const float4 v1 = *(const float4*)(src + (size_t)i * 8 + 4);
    const bf16x8 pk = {
        (short)f2bf(v0.x), (short)f2bf(v0.y), (short)f2bf(v0.z), (short)f2bf(v0.w),
        (short)f2bf(v1.x), (short)f2bf(v1.y), (short)f2bf(v1.z), (short)f2bf(v1.w)};
    *(bf16x8*)(dst + (size_t)i * 8) = pk;
}

// ---------------------------------------------------------------------------
// Weight transpose+convert: W[k][N] f32 -> T[n][256] bf16.
// z=0 value_W(256), z=1 out_W(256), z=2 off_W(512)->qk_Wt[0:512],
// z=3 attw_W(256)->qk_Wt[512:768].  grid (8, 16, 4), block 256.
// ---------------------------------------------------------------------------
__global__ __launch_bounds__(256) void transpose_w(
    const float* __restrict__ Wv, const float* __restrict__ Wo,
    const float* __restrict__ Wf, const float* __restrict__ Wa,
    ushort_t* __restrict__ Tv, ushort_t* __restrict__ To,
    ushort_t* __restrict__ Tqk) {
    const int z = blockIdx.z;
    const float* W;
    ushort_t* T;
    int N;
    if (z == 0)      { W = Wv; T = Tv;              N = 256; }
    else if (z == 1) { W = Wo; T = To;              N = 256; }
    else if (z == 2) { W = Wf; T = Tqk;             N = 512; }
    else             { W = Wa; T = Tqk + 512 * 256; N = 256; }
    const int n0 = blockIdx.y * 32;
    if (n0 >= N) return;
    const int k0 = blockIdx.x * 32;

    __shared__ float tile[32][33];
    const int tx = threadIdx.x & 31;
    const int ty = threadIdx.x >> 5;   // 0..7

    #pragma unroll
    for (int r = 0; r < 4; ++r) {
        const int k = ty + r * 8;
        tile[k][tx] = W[(size_t)(k0 + k) * N + n0 + tx];
    }
    __syncthreads();
    #pragma unroll
    for (int r = 0; r < 4; ++r) {
        const int n = ty + r * 8;
        T[(size_t)(n0 + n) * 256 + k0 + tx] = f2bf(tile[tx][n]);
    }
}

// ---------------------------------------------------------------------------
// MFMA GEMM: C[M,N] = A[M,256] @ W[256,N] + bias (+resid).
// A bf16 [M][256]; Wt bf16 [N][256]. N multiple of 128.
// bias: f32, column gn takes bias0[gn] if gn<split else bias1[gn-split].
// Double-buffered LDS, register prefetch of next K-tile.
// ---------------------------------------------------------------------------
template <bool OUT_BF16, bool RESID>
__global__ __launch_bounds__(256) void gemm_mfma(
    const ushort_t* __restrict__ A, const ushort_t* __restrict__ Wt,
    const float* __restrict__ bias0, const float* __restrict__ bias1, int split,
    const float* __restrict__ resid, void* __restrict__ Cv, int M, int N) {
    __shared__ ushort_t sA[2][128][32];
    __shared__ ushort_t sB[2][128][32];

    const int m0 = blockIdx.x * 128;
    const int n0 = blockIdx.y * 128;
    const int t    = threadIdx.x;
    const int lane = t & 63;
    const int w    = t >> 6;
    const int wr   = w >> 1, wc = w & 1;

    const int srow = t >> 2;          // 0..63
    const int skof = (t & 3) * 8;     // 0,8,16,24

    const bool am0 = (m0 + srow) < M;
    const bool am1 = (m0 + 64 + srow) < M;
    const ushort_t* Ap0 = A + (size_t)(m0 + srow) * 256 + skof;
    const ushort_t* Ap1 = Ap0 + (size_t)64 * 256;
    const ushort_t* Bp0 = Wt + (size_t)(n0 + srow) * 256 + skof;
    const ushort_t* Bp1 = Bp0 + (size_t)64 * 256;

    f32x4 acc[4][4];
    #pragma unroll
    for (int i = 0; i < 4; ++i)
        #pragma unroll
        for (int j = 0; j < 4; ++j)
            acc[i][j] = (f32x4){0.f, 0.f, 0.f, 0.f};

    const bf16x8 zz = {0, 0, 0, 0, 0, 0, 0, 0};

    // prologue: tile 0 -> LDS[0]
    {
        const bf16x8 a0 = am0 ? *(const bf16x8*)(Ap0) : zz;
        const bf16x8 a1 = am1 ? *(const bf16x8*)(Ap1) : zz;
        const bf16x8 b0 = *(const bf16x8*)(Bp0);
        const bf16x8 b1 = *(const bf16x8*)(Bp1);
        *(bf16x8*)(&sA[0][srow][skof])      = a0;
        *(bf16x8*)(&sA[0][64 + srow][skof]) = a1;
        *(bf16x8*)(&sB[0][srow][skof])      = b0;
        *(bf16x8*)(&sB[0][64 + srow][skof]) = b1;
    }
    __syncthreads();

    const int rl = lane & 15;
    const int kq = (lane >> 4) * 8;

    for (int k = 0; k < 8; ++k) {
        const int buf = k & 1;

        // issue next tile's global loads early (land during MFMA below)
        bf16x8 na0 = zz, na1 = zz, nb0 = zz, nb1 = zz;
        if (k < 7) {
            const int ko = (k + 1) * 32;
            if (am0) na0 = *(const bf16x8*)(Ap0 + ko);
            if (am1) na1 = *(const bf16x8*)(Ap1 + ko);
            nb0 = *(const bf16x8*)(Bp0 + ko);
            nb1 = *(const bf16x8*)(Bp1 + ko);
        }

        bf16x8 af[4], bfr[4];
        #pragma unroll
        for (int i = 0; i < 4; ++i)
            af[i] = *(const bf16x8*)(&sA[buf][wr * 64 + i * 16 + rl][kq]);
        #pragma unroll
        for (int j = 0; j < 4; ++j)
            bfr[j] = *(const bf16x8*)(&sB[buf][wc * 64 + j * 16 + rl][kq]);
        #pragma unroll
        for (int i = 0; i < 4; ++i)
            #pragma unroll
            for (int j = 0; j < 4; ++j)
                acc[i][j] = __builtin_amdgcn_mfma_f32_16x16x32_bf16(
                    af[i], bfr[j], acc[i][j], 0, 0, 0);

        if (k < 7) {
            __syncthreads();   // all waves done reading buf^1 (from k-1)
            *(bf16x8*)(&sA[buf ^ 1][srow][skof])      = na0;
            *(bf16x8*)(&sA[buf ^ 1][64 + srow][skof]) = na1;
            *(bf16x8*)(&sB[buf ^ 1][srow][skof])      = nb0;
            *(bf16x8*)(&sB[buf ^ 1][64 + srow][skof]) = nb1;
            __syncthreads();   // writes visible for next iteration
        }
    }

    // --- epilogue: C/D layout col=lane&15, row=(lane>>4)*4+reg (m89) ---
    const int col_l = lane & 15;
    const int rq    = (lane >> 4) * 4;
    #pragma unroll
    for (int j = 0; j < 4; ++j) {
        const int gn = n0 + wc * 64 + j * 16 + col_l;
        const float bj = (gn < split) ? bias0[gn] : bias1[gn - split];
        #pragma unroll
        for (int i = 0; i < 4; ++i) {
            #pragma unroll
            for (int r = 0; r < 4; ++r) {
                const int gm = m0 + wr * 64 + i * 16 + rq + r;
                if (gm >= M) continue;
                float v = acc[i][j][r] + bj;
                if (RESID) v += resid[(size_t)gm * N + gn];
                if (OUT_BF16)
                    ((ushort_t*)Cv)[(size_t)gm * N + gn] = f2bf(v);
                else
                    ((float*)Cv)[(size_t)gm * N + gn] = v;
            }
        }
    }
}

// ---------------------------------------------------------------------------
// Deformable sampling. 1 block per query, 256 threads.
//   setup role : (h, lp = tid&31)  -> corner idx/weights for its (h,lvl,p)
//   gather role: (h, slice, g)     -> 16B dwordx4 loads of 8 bf16 channels
// Reads offsets/attw from fused qkcat [10000][768] (cols 0..511 off, 512.. att).
// Writes slots as bf16.
// ---------------------------------------------------------------------------
__global__ __launch_bounds__(256) void sample_k(
    const float* __restrict__ qkcat,    // [10000, 768]
    const float* __restrict__ refp,     // f32 [6,1,10000,4,2]
    const int* __restrict__ vox,        // int32 [6,1,10000,4]
    const ushort_t* __restrict__ vproj, // bf16 [6*5440, 256]
    ushort_t* __restrict__ slots) {     // bf16 [10000, 256]
    const int q   = blockIdx.x;
    const int tid = threadIdx.x;
    const int h     = tid >> 5;
    const int lp    = tid & 31;          // setup role
    const int slice = (tid >> 2) & 7;    // gather role
    const int g     = tid & 3;           // gather role: channels g*8..g*8+7

    __shared__ float s_valid[8];
    __shared__ int   s_ci[4][256];       // [corner][h*32+lp]
    __shared__ float s_cw[4][256];
    __shared__ float s_red[256][8];      // [tid][chan-in-group]

    if (tid < 6) {
        const int base = (tid * 10000 + q) * 4;
        const int mm = vox[base] | vox[base + 1] | vox[base + 2] | vox[base + 3];
        s_valid[tid] = mm ? 1.0f : 0.0f;
    }

    // ---- softmax over 32 (lvl,p) entries within each head ----
    const float a = qkcat[(size_t)q * 768 + 512 + tid];
    float mx = a;
    #pragma unroll
    for (int o = 16; o >= 1; o >>= 1) mx = fmaxf(mx, __shfl_xor(mx, o));
    const float e = __expf(a - mx);
    float se = e;
    #pragma unroll
    for (int o = 16; o >= 1; o >>= 1) se += __shfl_xor(se, o);
    const float aw = e / se;

    // ---- camera-independent part of this thread's sample location ----
    const int lvl = lp >> 3;
    const int p   = lp & 7;
    const int dd  = p & 3;
    const int   Sarr[4]   = {64, 32, 16, 8};
    const int   Lstart[4] = {0, 4096, 5120, 5376};
    const int   S  = Sarr[lvl];
    const float Sf = (float)S;
    const int   lstart = Lstart[lvl];
    const float ox = qkcat[(size_t)q * 768 + h * 64 + lvl * 16 + p * 2 + 0] / Sf;
    const float oy = qkcat[(size_t)q * 768 + h * 64 + lvl * 16 + p * 2 + 1] / Sf;

    __syncthreads();
    const float cnt = s_valid[0] + s_valid[1] + s_valid[2] +
                      s_valid[3] + s_valid[4] + s_valid[5];

    float acc[8] = {};
    const int gofs = g << 3;

    for (int c = 0; c < 6; ++c) {
        if (s_valid[c] == 0.0f) continue;   // block-uniform branch

        {
            const int rbase = ((c * 10000 + q) * 4 + dd) * 2;
            const float rx = refp[rbase + 0];
            const float ry = refp[rbase + 1];
            const float x  = (rx + ox) * Sf - 0.5f;
            const float y  = (ry + oy) * Sf - 0.5f;
            const float x0 = floorf(x), y0 = floorf(y);
            #pragma unroll
            for (int k = 0; k < 4; ++k) {
                const float cx = x0 + (float)(k & 1);
                const float cy = y0 + (float)(k >> 1);
                const float wgt = (1.0f - fabsf(x - cx)) * (1.0f - fabsf(y - cy));
                const bool ok = (cx >= 0.0f) & (cx < Sf) & (cy >= 0.0f) & (cy < Sf);
                const int xi = (int)fminf(fmaxf(cx, 0.0f), Sf - 1.0f);
                const int yi = (int)fminf(fmaxf(cy, 0.0f), Sf - 1.0f);
                s_ci[k][tid] = (c * 5440 + lstart + yi * S + xi) * 256 + h * 32;
                s_cw[k][tid] = ok ? wgt * aw : 0.0f;
            }
        }
        __syncthreads();

        #pragma unroll
        for (int j = 0; j < 4; ++j) {
            const int el = h * 32 + slice * 4 + j;
            #pragma unroll
            for (int k = 0; k < 4; ++k) {
                const int   idx = s_ci[k][el];
                const float wv  = s_cw[k][el];
                const uint4 v = *(const uint4*)(vproj + idx + gofs);
                acc[0] += wv * __uint_as_float(v.x << 16);
                acc[1] += wv * __uint_as_float(v.x & 0xffff0000u);
                acc[2] += wv * __uint_as_float(v.y << 16);
                acc[3] += wv * __uint_as_float(v.y & 0xffff0000u);
                acc[4] += wv * __uint_as_float(v.z << 16);
                acc[5] += wv * __uint_as_float(v.z & 0xffff0000u);
                acc[6] += wv * __uint_as_float(v.w << 16);
                acc[7] += wv * __uint_as_float(v.w & 0xffff0000u);
            }
        }
        __syncthreads();
    }

    // ---- cross-slice reduction ----
    #pragma unroll
    for (int e2 = 0; e2 < 8; ++e2) s_red[tid][e2] = acc[e2];
    __syncthreads();

    const int cch = tid & 31;
    float sum = 0.0f;
    #pragma unroll
    for (int s = 0; s < 8; ++s)
        sum += s_red[h * 32 + s * 4 + (cch >> 3)][cch & 7];

    slots[(size_t)q * 256 + tid] = f2bf(sum / fmaxf(cnt, 1.0f));
}

// ---------------------------------------------------------------------------
extern "C" void kernel_launch(void* const* d_in, const int* in_sizes, int n_in,
                              void* d_out, int out_size, void* d_ws, size_t ws_size,
                              hipStream_t stream) {
    const float* query   = (const float*)d_in[0];
    // d_in[1] = key : unused by the deformable-attention math
    const float* value   = (const float*)d_in[2];   // (6,5440,1,256) -> (32640,256)
    const float* refp    = (const float*)d_in[3];
    const int*   vox     = (const int*)d_in[4];
    // d_in[5] spatial_shapes, d_in[6] level_start_index : compile-time constants
    const float* value_W = (const float*)d_in[7];
    const float* value_b = (const float*)d_in[8];
    const float* off_W   = (const float*)d_in[9];
    const float* off_b   = (const float*)d_in[10];
    const float* attw_W  = (const float*)d_in[11];
    const float* attw_b  = (const float*)d_in[12];
    const float* out_W   = (const float*)d_in[13];
    const float* out_b   = (const float*)d_in[14];
    float* out = (float*)d_out;

    // ws layout (bytes), with liveness-based aliasing:
    //   [0, 16711680)                 vproj bf16 [32640][256]
    //   [16711680, 47431680)          R1: value_bf bf16 (16.7MB, dead after gemm1)
    //                                     then qkcat f32 [10000][768] (30.7MB)
    //   [47431680, 52551680)          R2: query_bf bf16 (dead after gemm2)
    //                                     then slots bf16 [10000][256]
    //   [52551680, ...)               value_Wt | out_Wt | qk_Wt  bf16
    char* ws = (char*)d_ws;
    ushort_t* vproj    = (ushort_t*)ws;
    ushort_t* value_bf = (ushort_t*)(ws + 16711680);
    float*    qkcat    = (float*)   (ws + 16711680);
    ushort_t* query_bf = (ushort_t*)(ws + 47431680);
    ushort_t* slots    = (ushort_t*)(ws + 47431680);
    ushort_t* value_Wt = (ushort_t*)(ws + 52551680);
    ushort_t* out_Wt   = (ushort_t*)(ws + 52551680 + 131072);
    ushort_t* qk_Wt    = (ushort_t*)(ws + 52551680 + 262144);

    // 1,2. f32 -> bf16 copies of A matrices
    cvt_bf16<<<4080, 256, 0, stream>>>(value, value_bf, 1044480);
    cvt_bf16<<<1250, 256, 0, stream>>>(query, query_bf, 320000);
    // 3. transpose+convert weights -> Wt[n][k] bf16 (off|attw fused)
    transpose_w<<<dim3(8, 16, 4), 256, 0, stream>>>(
        value_W, out_W, off_W, attw_W, value_Wt, out_Wt, qk_Wt);
    // 4. value projection: 32640 x 256 x 256, bf16 out
    gemm_mfma<true, false><<<dim3(255, 2), 256, 0, stream>>>(
        value_bf, value_Wt, value_b, value_b, 256, nullptr,
        (void*)vproj, 32640, 256);
    // 5. fused offset+attw projection: 10000 x 256 x 768, f32 out
    gemm_mfma<false, false><<<dim3(79, 6), 256, 0, stream>>>(
        query_bf, qk_Wt, off_b, attw_b, 512, nullptr,
        (void*)qkcat, 10000, 768);
    // 6. deformable sampling + softmax + camera mask/count -> bf16 slots
    sample_k<<<10000, 256, 0, stream>>>(qkcat, refp, vox, vproj, slots);
    // 7. output projection + residual, f32 out
    gemm_mfma<false, true><<<dim3(79, 2), 256, 0, stream>>>(
        slots, out_Wt, out_b, out_b, 256, query, (void*)out, 10000, 256);
}